// Round 13
// baseline (38.524 us; speedup 1.0000x reference)
//
#include <hip/hip_runtime.h>
#include <math.h>

#define N_ATOMS 4096
#define CUTOFF2 25.0f
#define NTILE   16               // i-tiles of 256
#define NJ      64               // j slices
#define JT      64               // j atoms per slice (= wave width)
#define LOG2E   1.4426950408889634f
#define LN2     0.6931471805599453f

__device__ __forceinline__ float pow20f(float t) {
    float t2 = t * t, t4 = t2 * t2, t8 = t4 * t4, t16 = t8 * t8;
    return t16 * t4;
}

__device__ __forceinline__ float rl(float v, int k) {   // broadcast lane k -> SGPR
    return __int_as_float(__builtin_amdgcn_readlane(__float_as_int(v), k));
}

// deterministic block reduction (256 threads); result broadcast via red[0..3]
__device__ __forceinline__ float block_reduce(float v, float* red) {
    __syncthreads();
    #pragma unroll
    for (int off = 32; off > 0; off >>= 1) v += __shfl_down(v, off, 64);
    if ((threadIdx.x & 63) == 0) red[threadIdx.x >> 6] = v;
    __syncthreads();
    return (red[0] + red[1]) + (red[2] + red[3]);
}

// K0: per-atom folded constants apk[a][16]:
//   row0 {x,y,z,rei}  row1 {c0b, c1bp=b*log2e+log2(fe), mla, 0}
//   row2 {c0a, c1a=al2, mka, A}  row3 {Bof=B/fe, 0,0,0}
__global__ __launch_bounds__(256) void pack_kernel(
    const float* __restrict__ coords, const float* __restrict__ params,
    float* __restrict__ apk)
{
    const int a = blockIdx.x * 256 + threadIdx.x;
    const float* p = params + 22 * a;
    const float rei  = __builtin_amdgcn_rcpf(p[0]);
    const float bl2  = p[5] * LOG2E;
    const float al2  = p[4] * LOG2E;
    float4* ad = (float4*)(apk + 16 * a);
    ad[0] = { coords[3*a], coords[3*a+1], coords[3*a+2], rei };
    ad[1] = { -bl2 * rei, bl2 + __builtin_amdgcn_logf(p[1]), -p[9], 0.0f };
    ad[2] = { -al2 * rei, al2, -p[8], p[6] };
    ad[3] = { p[7] * __builtin_amdgcn_rcpf(p[1]), 0.0f, 0.0f, 0.0f };
}

// K1: rho via readlane-broadcast j-constants (no LDS in hot loop), phi via
// per-lane ctz over hit bitmask reading small LDS table. grid (16,64) x 256.
__global__ __launch_bounds__(256) void eam_main(
    const float* __restrict__ apk,
    float* __restrict__ rho_part,    // [NJ][N_ATOMS]
    float* __restrict__ e_part)      // [NTILE*NJ]
{
    __shared__ float4 sphi4[JT * 4];   // 4 KB: phi constants for the slice
    __shared__ float red[4];

    const int tid  = threadIdx.x;
    const int bi   = blockIdx.x;     // 0..15
    const int s    = blockIdx.y;     // 0..63
    const int i    = bi * 256 + tid;
    const int lane = tid & 63;
    const int jbase = s * JT;

    const float4* apk4 = (const float4*)apk;
    sphi4[tid] = apk4[jbase * 4 + tid];          // 256 float4, coalesced

    // this lane's j-atom rho constants (lane l <-> j = jbase+l)
    const float4 j0 = apk4[(jbase + lane) * 4 + 0];   // x,y,z,rei
    const float4 j1 = apk4[(jbase + lane) * 4 + 1];   // c0b,c1bp,mla,0

    // i-side constants
    const float4 a0 = apk4[i * 4 + 0];
    const float4 a1 = apk4[i * 4 + 1];
    const float4 a2 = apk4[i * 4 + 2];
    const float4 a3 = apk4[i * 4 + 3];

    __syncthreads();

    float rhoA = 0.0f, rhoB = 0.0f;
    unsigned int m_lo = 0u, m_hi = 0u;

    #pragma unroll 8
    for (int k = 0; k < JT; ++k) {
        const float xj  = rl(j0.x, k), yj = rl(j0.y, k), zj = rl(j0.z, k);
        const float rej = rl(j0.w, k);
        const float c0b = rl(j1.x, k), c1b = rl(j1.y, k), mla = rl(j1.z, k);

        const float dx = xj - a0.x;
        const float dy = yj - a0.y;
        const float dz = zj - a0.z;
        const float r2 = fmaf(dx, dx, fmaf(dy, dy, dz * dz));
        const float r  = __builtin_amdgcn_sqrtf(r2);
        const float ev = __builtin_amdgcn_exp2f(fmaf(r, c0b, c1b));
        const float dv = __builtin_amdgcn_rcpf(1.0f + pow20f(fmaf(r, rej, mla)));
        if (k & 1) rhoB = fmaf(ev, dv, rhoB); else rhoA = fmaf(ev, dv, rhoA);

        const bool hit = (r2 <= CUTOFF2);
        if (k < 32) m_lo |= hit ? (1u << k) : 0u;
        else        m_hi |= hit ? (1u << (k - 32)) : 0u;
    }

    float rho = rhoA + rhoB;
    const int t = i - jbase;
    if (t >= 0 && t < JT) {   // remove self term (r=0)
        rho -= __builtin_amdgcn_exp2f(a1.y)
             * __builtin_amdgcn_rcpf(1.0f + pow20f(a1.z));
    }
    rho_part[(size_t)s * N_ATOMS + i] = rho;

    // keep only j > i bits (each unordered pair once)
    if (t >= 63)      { m_lo = 0u; m_hi = 0u; }
    else if (t >= 32) { m_lo = 0u; m_hi &= ~((2u << (t - 32)) - 1u); }
    else if (t >= 0)  { m_lo &= ~((2u << t) - 1u); }

    const float* sphi = (const float*)sphi4;
    float e = 0.0f;
    #pragma unroll 1
    for (int half = 0; half < 2; ++half) {
        unsigned int m = half ? m_hi : m_lo;
        const int kofs = half ? 32 : 0;
        while (m) {
            const int k = __builtin_ctz(m) + kofs;
            m &= m - 1;
            const float4 q0 = *(const float4*)&sphi[k * 16];       // x,y,z,rei
            const float4 q1 = *(const float4*)&sphi[k * 16 + 4];   // c0b,c1bp,mla,0
            const float4 q2 = *(const float4*)&sphi[k * 16 + 8];   // c0a,c1a,mka,A
            const float Bof_j = sphi[k * 16 + 12];

            const float dx = q0.x - a0.x, dy = q0.y - a0.y, dz = q0.z - a0.z;
            const float r = __builtin_amdgcn_sqrtf(fmaf(dx, dx, fmaf(dy, dy, dz * dz)));

            const float fri = __builtin_amdgcn_exp2f(fmaf(r, a1.x, a1.y))
                            * __builtin_amdgcn_rcpf(1.0f + pow20f(fmaf(r, a0.w, a1.z)));
            const float frj = __builtin_amdgcn_exp2f(fmaf(r, q1.x, q1.y))
                            * __builtin_amdgcn_rcpf(1.0f + pow20f(fmaf(r, q0.w, q1.z)));
            const float ph_i = a2.w * __builtin_amdgcn_exp2f(fmaf(r, a2.x, a2.y))
                                    * __builtin_amdgcn_rcpf(1.0f + pow20f(fmaf(r, a0.w, a2.z)))
                             - a3.x * fri;
            const float ph_j = q2.w * __builtin_amdgcn_exp2f(fmaf(r, q2.x, q2.y))
                                    * __builtin_amdgcn_rcpf(1.0f + pow20f(fmaf(r, q0.w, q2.z)))
                             - Bof_j * frj;
            // frj/fri*ph_i + fri/frj*ph_j = (frj^2*ph_i + fri^2*ph_j)/(fri*frj)
            e += 0.5f * fmaf(frj * frj, ph_i, fri * fri * ph_j)
                      * __builtin_amdgcn_rcpf(fri * frj);
        }
    }

    const float eb = block_reduce(e, red);
    if (tid == 0) e_part[bi * NJ + s] = eb;
}

// K2: embed + per-tile e reduction. 16 blocks x 256 threads.
__global__ __launch_bounds__(256) void eam_embed(
    const float* __restrict__ params,
    const float* __restrict__ rho_part, const float* __restrict__ e_part,
    float* __restrict__ tile_sum)    // [16]
{
    __shared__ float red[4];
    const int tid = threadIdx.x;
    const int b   = blockIdx.x;
    const int i   = b * 256 + tid;

    float s0 = 0.0f, s1 = 0.0f, s2 = 0.0f, s3 = 0.0f;
    #pragma unroll 4
    for (int t = 0; t < NJ; t += 4) {   // coalesced per slice
        s0 += rho_part[(size_t)(t + 0) * N_ATOMS + i];
        s1 += rho_part[(size_t)(t + 1) * N_ATOMS + i];
        s2 += rho_part[(size_t)(t + 2) * N_ATOMS + i];
        s3 += rho_part[(size_t)(t + 3) * N_ATOMS + i];
    }
    const float rhoi = (s0 + s1) + (s2 + s3);

    const float* p = params + 22 * i;
    float F;
    if (rhoi < p[20]) {
        const float xn = rhoi / p[20] - 1.0f;
        F = p[10] + xn * (p[11] + xn * (p[12] + xn * p[13]));
    } else if (rhoi < p[21]) {
        const float xe = rhoi / p[2] - 1.0f;
        F = p[14] + xe * (p[15] + xe * (p[16] + xe * p[17]));
    } else {
        const float l2 = __builtin_amdgcn_logf(rhoi / p[3]);   // log2
        const float t  = __builtin_amdgcn_exp2f(p[18] * l2);
        const float lt = p[18] * l2 * LN2;                     // ln
        F = p[19] * (1.0f - lt) * t;
    }

    // e_part has NTILE*NJ = 1024 entries; each of 16 blocks sums a 64-chunk
    float acc = F + ((tid < NJ) ? e_part[b * NJ + tid] : 0.0f);
    const float tot = block_reduce(acc, red);
    if (tid == 0) tile_sum[b] = tot;
}

// K3: final fixed-order sum of 16 tile sums (single wave)
__global__ __launch_bounds__(64) void eam_final(
    const float* __restrict__ tile_sum, float* __restrict__ out)
{
    const int tid = threadIdx.x;
    float acc = (tid < NTILE) ? tile_sum[tid] : 0.0f;
    #pragma unroll
    for (int off = 8; off > 0; off >>= 1) acc += __shfl_down(acc, off, 64);
    if (tid == 0) out[0] = acc;
}

extern "C" void kernel_launch(void* const* d_in, const int* in_sizes, int n_in,
                              void* d_out, int out_size, void* d_ws, size_t ws_size,
                              hipStream_t stream) {
    const float* coords = (const float*)d_in[0];   // [4096][3]
    const float* params = (const float*)d_in[1];   // [4096][22]
    float* out = (float*)d_out;

    float* apk      = (float*)d_ws;                          // [4096][16]
    float* rho_part = apk + (size_t)N_ATOMS * 16;            // [64][4096]
    float* e_part   = rho_part + (size_t)NJ * N_ATOMS;       // [1024]
    float* tile_sum = e_part + NTILE * NJ;                   // [16]

    pack_kernel<<<N_ATOMS / 256, 256, 0, stream>>>(coords, params, apk);
    dim3 grid(NTILE, NJ);
    eam_main<<<grid, 256, 0, stream>>>(apk, rho_part, e_part);
    eam_embed<<<16, 256, 0, stream>>>(params, rho_part, e_part, tile_sum);
    eam_final<<<1, 64, 0, stream>>>(tile_sum, out);
}

// Round 14
// 23.358 us; speedup vs baseline: 1.6493x; 1.6493x over previous
//
#include <hip/hip_runtime.h>
#include <math.h>

#define N_ATOMS 4096
#define NTILE   16               // i-tiles of 256
#define NJ      128              // j slices
#define JT      32               // j atoms per slice
#define LOG2E   1.4426950408889634f
#define LN2     0.6931471805599453f

typedef float v2f __attribute__((ext_vector_type(2)));

__device__ __forceinline__ float pow20f(float t) {
    float t2 = t * t, t4 = t2 * t2, t8 = t4 * t4, t16 = t8 * t8;
    return t16 * t4;
}

// deterministic block reduction (256 threads); result broadcast via red[0..3]
__device__ __forceinline__ float block_reduce(float v, float* red) {
    __syncthreads();
    #pragma unroll
    for (int off = 32; off > 0; off >>= 1) v += __shfl_down(v, off, 64);
    if ((threadIdx.x & 63) == 0) red[threadIdx.x >> 6] = v;
    __syncthreads();
    return (red[0] + red[1]) + (red[2] + red[3]);
}

// K0: per-atom folded constants + certified cutoff radius rc (f_r(rc) < 1e-6).
// apk[a][12]: row0 {x,y,z,rei}  row1 {c0b, c1bp=b*l2e+log2(fe), mla, Bof=B/fe}
//            row2 {c0a, c1a=al2, mka, A}
// rpk[pair][8]: [x0,x1,y0,y1 | z0,z1,rc2_0,rc2_1]
__global__ __launch_bounds__(256) void pack_kernel(
    const float* __restrict__ coords, const float* __restrict__ params,
    float* __restrict__ apk, float* __restrict__ rpk)
{
    const int a = blockIdx.x * 256 + threadIdx.x;
    const float* p = params + 22 * a;
    const float x = coords[3*a], y = coords[3*a+1], z = coords[3*a+2];
    const float re = p[0], fe = p[1], be = p[5], al = p[4], la = p[9];
    const float rei  = __builtin_amdgcn_rcpf(re);
    const float bl2  = be * LOG2E;
    const float al2  = al * LOG2E;
    const float l2fe = __builtin_amdgcn_logf(fe);   // log2

    // bisection: g(x) = l2fe - bl2*(x-1) - log2(1+(x-la)^20) + 19.93  (f = 1e-6)
    float lo = la + 1.0f, hi = la + 6.0f;
    #pragma unroll 1
    for (int it = 0; it < 28; ++it) {
        const float mid = 0.5f * (lo + hi);
        const float t   = mid - la;
        const float g   = l2fe - bl2 * (mid - 1.0f)
                        - __builtin_amdgcn_logf(1.0f + pow20f(t)) + 19.93f;
        if (g > 0.0f) lo = mid; else hi = mid;
    }
    const float rc  = re * hi;            // conservative side
    const float rc2 = fmaxf(rc * rc, 25.01f);   // phi-set (r<=5) always included

    float4* ad = (float4*)(apk + 12 * a);
    ad[0] = { x, y, z, rei };
    ad[1] = { -bl2 * rei, bl2 + l2fe, -la, p[7] * __builtin_amdgcn_rcpf(fe) };
    ad[2] = { -al2 * rei, al2, -p[8], p[6] };

    float* rd = rpk + 8 * (a >> 1) + (a & 1);
    rd[0] = x; rd[2] = y; rd[4] = z; rd[6] = rc2;
}

// K1: sparsified rho + phi. grid (16,128) x 256. Thread owns i = bi*256+tid.
// phase1: r^2 vs rc2 over 16 j-pairs (packed) -> 32-bit hit mask.
// phase2a: ctz over hits, full f_r eval (~1.8% of pairs), sets phi bits.
// phase2b: ctz over phi bits (j>i), full phi eval.
__global__ __launch_bounds__(256) void eam_main(
    const float* __restrict__ apk, const float* __restrict__ rpk,
    float* __restrict__ rho_part,    // [NJ][N_ATOMS]
    float* __restrict__ e_part)      // [NTILE*NJ]
{
    __shared__ float4 srho4[JT / 2 * 2];   // 32 float4 = 512 B
    __shared__ float4 sphi4[JT * 3];       // 96 float4 = 1.5 KB
    __shared__ float red[4];

    const int tid = threadIdx.x;
    const int bi  = blockIdx.x;      // 0..15
    const int s   = blockIdx.y;      // 0..127
    const int i   = bi * 256 + tid;
    const int jbase = s * JT;

    if (tid < 32)                     srho4[tid]      = ((const float4*)rpk)[s * 32 + tid];
    else if (tid >= 64 && tid < 160)  sphi4[tid - 64] = ((const float4*)apk)[s * 96 + (tid - 64)];

    const float4* apk4 = (const float4*)apk;
    const float4 a0 = apk4[i * 3 + 0];   // x,y,z,rei
    const float4 a1 = apk4[i * 3 + 1];   // c0b,c1bp,mla,Bof
    const float4 a2 = apk4[i * 3 + 2];   // c0a,c1a,mka,A

    __syncthreads();

    const v2f xi2 = { a0.x, a0.x }, yi2 = { a0.y, a0.y }, zi2 = { a0.z, a0.z };
    unsigned int hits = 0u;

    #pragma unroll 4
    for (int k = 0; k < JT / 2; ++k) {
        const float4 f0 = srho4[k * 2 + 0];   // x0,x1,y0,y1
        const float4 f1 = srho4[k * 2 + 1];   // z0,z1,rc2_0,rc2_1
        const v2f x01 = { f0.x, f0.y }, y01 = { f0.z, f0.w };
        const v2f z01 = { f1.x, f1.y };
        const v2f dx = x01 - xi2, dy = y01 - yi2, dz = z01 - zi2;
        const v2f r2v = dx * dx + dy * dy + dz * dz;
        if (r2v.x <= f1.z) hits |= (1u << (2 * k));
        if (r2v.y <= f1.w) hits |= (1u << (2 * k + 1));
    }

    const int t = i - jbase;   // slice-local index of i (may be out of range)
    float rho = 0.0f;
    unsigned int phim = 0u;

    {   // phase2a: f_r for hit pairs
        unsigned int m = hits;
        if (t >= 0 && t < JT) m &= ~(1u << t);   // skip self (r=0)
        while (m) {
            const int k = __builtin_ctz(m);
            m &= m - 1;
            const float4 q0 = sphi4[k * 3 + 0];   // x,y,z,rei
            const float4 q1 = sphi4[k * 3 + 1];   // c0b,c1bp,mla,Bof
            const float dx = q0.x - a0.x, dy = q0.y - a0.y, dz = q0.z - a0.z;
            const float r2 = fmaf(dx, dx, fmaf(dy, dy, dz * dz));
            const float r  = __builtin_amdgcn_sqrtf(r2);
            const float fr = __builtin_amdgcn_exp2f(fmaf(r, q1.x, q1.y))
                           * __builtin_amdgcn_rcpf(1.0f + pow20f(fmaf(r, q0.w, q1.z)));
            rho += fr;
            if (r2 <= 25.0f && k > t) phim |= (1u << k);
        }
    }
    rho_part[(size_t)s * N_ATOMS + i] = rho;

    float e = 0.0f;
    while (phim) {   // phase2b: phi for pairs within 5 A, j > i
        const int k = __builtin_ctz(phim);
        phim &= phim - 1;
        const float4 q0 = sphi4[k * 3 + 0];
        const float4 q1 = sphi4[k * 3 + 1];
        const float4 q2 = sphi4[k * 3 + 2];
        const float dx = q0.x - a0.x, dy = q0.y - a0.y, dz = q0.z - a0.z;
        const float r = __builtin_amdgcn_sqrtf(fmaf(dx, dx, fmaf(dy, dy, dz * dz)));

        const float fri = __builtin_amdgcn_exp2f(fmaf(r, a1.x, a1.y))
                        * __builtin_amdgcn_rcpf(1.0f + pow20f(fmaf(r, a0.w, a1.z)));
        const float frj = __builtin_amdgcn_exp2f(fmaf(r, q1.x, q1.y))
                        * __builtin_amdgcn_rcpf(1.0f + pow20f(fmaf(r, q0.w, q1.z)));
        const float ph_i = a2.w * __builtin_amdgcn_exp2f(fmaf(r, a2.x, a2.y))
                                * __builtin_amdgcn_rcpf(1.0f + pow20f(fmaf(r, a0.w, a2.z)))
                         - a1.w * fri;
        const float ph_j = q2.w * __builtin_amdgcn_exp2f(fmaf(r, q2.x, q2.y))
                                * __builtin_amdgcn_rcpf(1.0f + pow20f(fmaf(r, q0.w, q2.z)))
                         - q1.w * frj;
        // frj/fri*ph_i + fri/frj*ph_j = (frj^2*ph_i + fri^2*ph_j)/(fri*frj)
        e += 0.5f * fmaf(frj * frj, ph_i, fri * fri * ph_j)
                  * __builtin_amdgcn_rcpf(fri * frj);
    }

    const float eb = block_reduce(e, red);
    if (tid == 0) e_part[bi * NJ + s] = eb;
}

// K2: embed + per-tile e reduction. 16 blocks x 1024 threads (4 threads per atom).
__global__ __launch_bounds__(1024) void eam_embed(
    const float* __restrict__ params,
    const float* __restrict__ rho_part, const float* __restrict__ e_part,
    float* __restrict__ tile_sum)    // [16]
{
    __shared__ float acc[4][256];
    __shared__ float red16[16];
    const int tid = threadIdx.x;
    const int b   = blockIdx.x;
    const int al  = tid & 255;       // atom within tile
    const int q   = tid >> 8;        // quarter 0..3
    const int i   = b * 256 + al;

    float part = 0.0f;
    #pragma unroll 8
    for (int s = q * 32; s < q * 32 + 32; ++s)
        part += rho_part[(size_t)s * N_ATOMS + i];   // coalesced per s
    acc[q][al] = part;
    __syncthreads();

    float v = 0.0f;
    if (tid < 256) {
        const float rhoi = (acc[0][tid] + acc[1][tid]) + (acc[2][tid] + acc[3][tid]);
        const float* p = params + 22 * i;
        float F;
        if (rhoi < p[20]) {
            const float xn = rhoi / p[20] - 1.0f;
            F = p[10] + xn * (p[11] + xn * (p[12] + xn * p[13]));
        } else if (rhoi < p[21]) {
            const float xe = rhoi / p[2] - 1.0f;
            F = p[14] + xe * (p[15] + xe * (p[16] + xe * p[17]));
        } else {
            const float l2 = __builtin_amdgcn_logf(rhoi / p[3]);   // log2
            const float tt = __builtin_amdgcn_exp2f(p[18] * l2);
            const float lt = p[18] * l2 * LN2;                     // ln
            F = p[19] * (1.0f - lt) * tt;
        }
        v = F + ((tid < NJ) ? e_part[b * NJ + tid] : 0.0f);
    }

    // deterministic reduction over 1024 threads (v = 0 for tid >= 256)
    #pragma unroll
    for (int off = 32; off > 0; off >>= 1) v += __shfl_down(v, off, 64);
    if ((tid & 63) == 0) red16[tid >> 6] = v;
    __syncthreads();
    if (tid == 0) {
        float s = 0.0f;
        #pragma unroll
        for (int w = 0; w < 16; ++w) s += red16[w];
        tile_sum[b] = s;
    }
}

// K3: final fixed-order sum of 16 tile sums (single wave)
__global__ __launch_bounds__(64) void eam_final(
    const float* __restrict__ tile_sum, float* __restrict__ out)
{
    const int tid = threadIdx.x;
    float acc = (tid < NTILE) ? tile_sum[tid] : 0.0f;
    #pragma unroll
    for (int off = 8; off > 0; off >>= 1) acc += __shfl_down(acc, off, 64);
    if (tid == 0) out[0] = acc;
}

extern "C" void kernel_launch(void* const* d_in, const int* in_sizes, int n_in,
                              void* d_out, int out_size, void* d_ws, size_t ws_size,
                              hipStream_t stream) {
    const float* coords = (const float*)d_in[0];   // [4096][3]
    const float* params = (const float*)d_in[1];   // [4096][22]
    float* out = (float*)d_out;

    float* apk      = (float*)d_ws;                          // [4096][12]
    float* rpk      = apk + (size_t)N_ATOMS * 12;            // [2048][8]
    float* rho_part = rpk + (size_t)(N_ATOMS / 2) * 8;       // [128][4096]
    float* e_part   = rho_part + (size_t)NJ * N_ATOMS;       // [2048]
    float* tile_sum = e_part + NTILE * NJ;                   // [16]

    pack_kernel<<<N_ATOMS / 256, 256, 0, stream>>>(coords, params, apk, rpk);
    dim3 grid(NTILE, NJ);
    eam_main<<<grid, 256, 0, stream>>>(apk, rpk, rho_part, e_part);
    eam_embed<<<NTILE, 1024, 0, stream>>>(params, rho_part, e_part, tile_sum);
    eam_final<<<1, 64, 0, stream>>>(tile_sum, out);
}

// Round 15
// 23.227 us; speedup vs baseline: 1.6586x; 1.0056x over previous
//
#include <hip/hip_runtime.h>
#include <math.h>

#define N_ATOMS 4096
#define NTILE   16               // i-tiles of 256
#define NJ      64               // j slices
#define JT      64               // j atoms per slice
#define LOG2E   1.4426950408889634f
#define LN2     0.6931471805599453f

typedef float v2f __attribute__((ext_vector_type(2)));
typedef unsigned long long u64;

__device__ __forceinline__ float pow20f(float t) {
    float t2 = t * t, t4 = t2 * t2, t8 = t4 * t4, t16 = t8 * t8;
    return t16 * t4;
}

// deterministic block reduction (256 threads); result broadcast via red[0..3]
__device__ __forceinline__ float block_reduce(float v, float* red) {
    __syncthreads();
    #pragma unroll
    for (int off = 32; off > 0; off >>= 1) v += __shfl_down(v, off, 64);
    if ((threadIdx.x & 63) == 0) red[threadIdx.x >> 6] = v;
    __syncthreads();
    return (red[0] + red[1]) + (red[2] + red[3]);
}

// K0: per-atom folded constants + certified cutoff radius rc (f_r(rc) < 1e-6).
// apk[a][12]: row0 {x,y,z,rei}  row1 {c0b, c1bp=b*l2e+log2(fe), mla, Bof=B/fe}
//            row2 {c0a, c1a=al2, mka, A}
// rpk[pair][8]: [x0,x1,y0,y1 | z0,z1,rc2_0,rc2_1]
__global__ __launch_bounds__(256) void pack_kernel(
    const float* __restrict__ coords, const float* __restrict__ params,
    float* __restrict__ apk, float* __restrict__ rpk, int* __restrict__ ctr)
{
    if (blockIdx.x == 0 && threadIdx.x == 0) *ctr = 0;
    const int a = blockIdx.x * 256 + threadIdx.x;
    const float* p = params + 22 * a;
    const float x = coords[3*a], y = coords[3*a+1], z = coords[3*a+2];
    const float re = p[0], fe = p[1], be = p[5], al = p[4], la = p[9];
    const float rei  = __builtin_amdgcn_rcpf(re);
    const float bl2  = be * LOG2E;
    const float al2  = al * LOG2E;
    const float l2fe = __builtin_amdgcn_logf(fe);   // log2

    // bisection: g(x) = l2fe - bl2*(x-1) - log2(1+(x-la)^20) + 19.93  (f = 1e-6)
    float lo = la + 1.0f, hi = la + 6.0f;
    #pragma unroll 1
    for (int it = 0; it < 28; ++it) {
        const float mid = 0.5f * (lo + hi);
        const float t   = mid - la;
        const float g   = l2fe - bl2 * (mid - 1.0f)
                        - __builtin_amdgcn_logf(1.0f + pow20f(t)) + 19.93f;
        if (g > 0.0f) lo = mid; else hi = mid;
    }
    const float rc  = re * hi;                 // conservative side
    const float rc2 = fmaxf(rc * rc, 25.01f);  // phi-set (r<=5) always included

    float4* ad = (float4*)(apk + 12 * a);
    ad[0] = { x, y, z, rei };
    ad[1] = { -bl2 * rei, bl2 + l2fe, -la, p[7] * __builtin_amdgcn_rcpf(fe) };
    ad[2] = { -al2 * rei, al2, -p[8], p[6] };

    float* rd = rpk + 8 * (a >> 1) + (a & 1);
    rd[0] = x; rd[2] = y; rd[4] = z; rd[6] = rc2;
}

// K1: sparsified rho + phi. grid (16,64) x 256. Thread owns i = bi*256+tid.
// phase1: r^2 vs rc2 over 32 j-pairs (packed) -> 64-bit hit mask.
// phase2a: ctz over hits, full f_r eval (~2% of pairs), sets phi bits.
// phase2b: ctz over phi bits (j>i), full phi eval.
__global__ __launch_bounds__(256) void eam_main(
    const float* __restrict__ apk, const float* __restrict__ rpk,
    float* __restrict__ rho_part,    // [NJ][N_ATOMS]
    float* __restrict__ e_part)      // [NTILE*NJ]
{
    __shared__ float4 srho4[JT];         // 64 float4 = 1 KB (32 pairs x 2)
    __shared__ float4 sphi4[JT * 3];     // 192 float4 = 3 KB
    __shared__ float red[4];

    const int tid = threadIdx.x;
    const int bi  = blockIdx.x;      // 0..15
    const int s   = blockIdx.y;      // 0..63
    const int i   = bi * 256 + tid;
    const int jbase = s * JT;

    if (tid < JT)       srho4[tid]      = ((const float4*)rpk)[s * JT + tid];
    else                sphi4[tid - 64] = ((const float4*)apk)[s * 192 + (tid - 64)];

    const float4* apk4 = (const float4*)apk;
    const float4 a0 = apk4[i * 3 + 0];   // x,y,z,rei
    const float4 a1 = apk4[i * 3 + 1];   // c0b,c1bp,mla,Bof
    const float4 a2 = apk4[i * 3 + 2];   // c0a,c1a,mka,A

    __syncthreads();

    const v2f xi2 = { a0.x, a0.x }, yi2 = { a0.y, a0.y }, zi2 = { a0.z, a0.z };
    u64 hits = 0ull;

    #pragma unroll 4
    for (int k = 0; k < JT / 2; ++k) {
        const float4 f0 = srho4[k * 2 + 0];   // x0,x1,y0,y1
        const float4 f1 = srho4[k * 2 + 1];   // z0,z1,rc2_0,rc2_1
        const v2f x01 = { f0.x, f0.y }, y01 = { f0.z, f0.w };
        const v2f z01 = { f1.x, f1.y };
        const v2f dx = x01 - xi2, dy = y01 - yi2, dz = z01 - zi2;
        const v2f r2v = dx * dx + dy * dy + dz * dz;
        if (r2v.x <= f1.z) hits |= (1ull << (2 * k));
        if (r2v.y <= f1.w) hits |= (1ull << (2 * k + 1));
    }

    const int t = i - jbase;   // slice-local index of i (may be out of range)
    float rho = 0.0f;
    u64 phim = 0ull;

    {   // phase2a: f_r for hit pairs
        u64 m = hits;
        if (t >= 0 && t < JT) m &= ~(1ull << t);   // skip self (r=0)
        while (m) {
            const int k = __builtin_ctzll(m);
            m &= m - 1;
            const float4 q0 = sphi4[k * 3 + 0];   // x,y,z,rei
            const float4 q1 = sphi4[k * 3 + 1];   // c0b,c1bp,mla,Bof
            const float dx = q0.x - a0.x, dy = q0.y - a0.y, dz = q0.z - a0.z;
            const float r2 = fmaf(dx, dx, fmaf(dy, dy, dz * dz));
            const float r  = __builtin_amdgcn_sqrtf(r2);
            const float fr = __builtin_amdgcn_exp2f(fmaf(r, q1.x, q1.y))
                           * __builtin_amdgcn_rcpf(1.0f + pow20f(fmaf(r, q0.w, q1.z)));
            rho += fr;
            if (r2 <= 25.0f && k > t) phim |= (1ull << k);
        }
    }
    rho_part[(size_t)s * N_ATOMS + i] = rho;

    float e = 0.0f;
    while (phim) {   // phase2b: phi for pairs within 5 A, j > i
        const int k = __builtin_ctzll(phim);
        phim &= phim - 1;
        const float4 q0 = sphi4[k * 3 + 0];
        const float4 q1 = sphi4[k * 3 + 1];
        const float4 q2 = sphi4[k * 3 + 2];
        const float dx = q0.x - a0.x, dy = q0.y - a0.y, dz = q0.z - a0.z;
        const float r = __builtin_amdgcn_sqrtf(fmaf(dx, dx, fmaf(dy, dy, dz * dz)));

        const float fri = __builtin_amdgcn_exp2f(fmaf(r, a1.x, a1.y))
                        * __builtin_amdgcn_rcpf(1.0f + pow20f(fmaf(r, a0.w, a1.z)));
        const float frj = __builtin_amdgcn_exp2f(fmaf(r, q1.x, q1.y))
                        * __builtin_amdgcn_rcpf(1.0f + pow20f(fmaf(r, q0.w, q1.z)));
        const float ph_i = a2.w * __builtin_amdgcn_exp2f(fmaf(r, a2.x, a2.y))
                                * __builtin_amdgcn_rcpf(1.0f + pow20f(fmaf(r, a0.w, a2.z)))
                         - a1.w * fri;
        const float ph_j = q2.w * __builtin_amdgcn_exp2f(fmaf(r, q2.x, q2.y))
                                * __builtin_amdgcn_rcpf(1.0f + pow20f(fmaf(r, q0.w, q2.z)))
                         - q1.w * frj;
        // frj/fri*ph_i + fri/frj*ph_j = (frj^2*ph_i + fri^2*ph_j)/(fri*frj)
        e += 0.5f * fmaf(frj * frj, ph_i, fri * fri * ph_j)
                  * __builtin_amdgcn_rcpf(fri * frj);
    }

    const float eb = block_reduce(e, red);
    if (tid == 0) e_part[bi * NJ + s] = eb;
}

// K2: embed + per-tile reduction + (last block) final sum. 16 blocks x 1024 threads.
__global__ __launch_bounds__(1024) void eam_embed(
    const float* __restrict__ params,
    const float* __restrict__ rho_part, const float* __restrict__ e_part,
    float* __restrict__ tile_sum,    // [16]
    int* __restrict__ ctr, float* __restrict__ out)
{
    __shared__ float acc[4][256];
    __shared__ float red16[16];
    __shared__ int sLast;
    const int tid = threadIdx.x;
    const int b   = blockIdx.x;
    const int al  = tid & 255;       // atom within tile
    const int q   = tid >> 8;        // quarter 0..3
    const int i   = b * 256 + al;

    float part = 0.0f;
    #pragma unroll 4
    for (int s = q * 16; s < q * 16 + 16; ++s)
        part += rho_part[(size_t)s * N_ATOMS + i];   // coalesced per s
    acc[q][al] = part;
    __syncthreads();

    float v = 0.0f;
    if (tid < 256) {
        const float rhoi = (acc[0][tid] + acc[1][tid]) + (acc[2][tid] + acc[3][tid]);
        const float* p = params + 22 * i;
        float F;
        if (rhoi < p[20]) {
            const float xn = rhoi / p[20] - 1.0f;
            F = p[10] + xn * (p[11] + xn * (p[12] + xn * p[13]));
        } else if (rhoi < p[21]) {
            const float xe = rhoi / p[2] - 1.0f;
            F = p[14] + xe * (p[15] + xe * (p[16] + xe * p[17]));
        } else {
            const float l2 = __builtin_amdgcn_logf(rhoi / p[3]);   // log2
            const float tt = __builtin_amdgcn_exp2f(p[18] * l2);
            const float lt = p[18] * l2 * LN2;                     // ln
            F = p[19] * (1.0f - lt) * tt;
        }
        v = F + ((tid < NJ) ? e_part[b * NJ + tid] : 0.0f);
    }

    // deterministic reduction over 1024 threads (v = 0 for tid >= 256)
    #pragma unroll
    for (int off = 32; off > 0; off >>= 1) v += __shfl_down(v, off, 64);
    if ((tid & 63) == 0) red16[tid >> 6] = v;
    __syncthreads();
    if (tid == 0) {
        float sum = 0.0f;
        #pragma unroll
        for (int w = 0; w < 16; ++w) sum += red16[w];
        tile_sum[b] = sum;
        // release: tile_sum visible device-wide before the count (16 blocks only)
        int prev = __hip_atomic_fetch_add(ctr, 1, __ATOMIC_ACQ_REL,
                                          __HIP_MEMORY_SCOPE_AGENT);
        sLast = (prev == NTILE - 1);
    }
    __syncthreads();

    if (sLast && tid == 0) {   // last block: fixed-order final sum
        float total = 0.0f;
        #pragma unroll
        for (int w = 0; w < NTILE; ++w) total += tile_sum[w];
        out[0] = total;
    }
}

extern "C" void kernel_launch(void* const* d_in, const int* in_sizes, int n_in,
                              void* d_out, int out_size, void* d_ws, size_t ws_size,
                              hipStream_t stream) {
    const float* coords = (const float*)d_in[0];   // [4096][3]
    const float* params = (const float*)d_in[1];   // [4096][22]
    float* out = (float*)d_out;

    float* apk      = (float*)d_ws;                          // [4096][12]
    float* rpk      = apk + (size_t)N_ATOMS * 12;            // [2048][8]
    float* rho_part = rpk + (size_t)(N_ATOMS / 2) * 8;       // [64][4096]
    float* e_part   = rho_part + (size_t)NJ * N_ATOMS;       // [1024]
    float* tile_sum = e_part + NTILE * NJ;                   // [16]
    int*   ctr      = (int*)(tile_sum + NTILE);              // [1]

    pack_kernel<<<N_ATOMS / 256, 256, 0, stream>>>(coords, params, apk, rpk, ctr);
    dim3 grid(NTILE, NJ);
    eam_main<<<grid, 256, 0, stream>>>(apk, rpk, rho_part, e_part);
    eam_embed<<<NTILE, 1024, 0, stream>>>(params, rho_part, e_part, tile_sum, ctr, out);
}

// Round 16
// 20.217 us; speedup vs baseline: 1.9055x; 1.1489x over previous
//
#include <hip/hip_runtime.h>
#include <math.h>

#define N_ATOMS 4096
#define NTILE   16               // i-tiles of 256
#define NJ      64               // j slices
#define JT      64               // j atoms per slice
#define LOG2E   1.4426950408889634f
#define LN2     0.6931471805599453f

typedef float v2f __attribute__((ext_vector_type(2)));
typedef unsigned long long u64;

__device__ __forceinline__ float pow20f(float t) {
    float t2 = t * t, t4 = t2 * t2, t8 = t4 * t4, t16 = t8 * t8;
    return t16 * t4;
}

// deterministic block reduction (256 threads); result broadcast via red[0..3]
__device__ __forceinline__ float block_reduce(float v, float* red) {
    __syncthreads();
    #pragma unroll
    for (int off = 32; off > 0; off >>= 1) v += __shfl_down(v, off, 64);
    if ((threadIdx.x & 63) == 0) red[threadIdx.x >> 6] = v;
    __syncthreads();
    return (red[0] + red[1]) + (red[2] + red[3]);
}

// K1: in-block pack (+certified rc2 bisection) + sparsified rho + phi.
// grid (16,64) x 256. Thread owns i = bi*256+tid.
// phase1: r^2 vs rc2 over 32 j-pairs (packed v2f) -> 64-bit hit mask.
// phase2a: ctz over hits, full f_r eval (~2% of pairs), sets phi bits.
// phase2b: ctz over phi bits (j>i), full phi eval.
__global__ __launch_bounds__(256) void eam_main(
    const float* __restrict__ coords, const float* __restrict__ params,
    float* __restrict__ rho_part,    // [NJ][N_ATOMS]
    float* __restrict__ e_part,      // [NTILE*NJ]
    int* __restrict__ ctr)
{
    __shared__ float4 srho4[JT];         // 32 pairs x 2 float4 = 1 KB
    __shared__ float4 sphi4[JT * 3];     // 3 KB
    __shared__ float red[4];

    const int tid = threadIdx.x;
    const int bi  = blockIdx.x;      // 0..15
    const int s   = blockIdx.y;      // 0..63
    const int i   = bi * 256 + tid;
    const int jbase = s * JT;

    if (bi == 0 && s == 0 && tid == 0) *ctr = 0;   // reset K2's counter (K1 precedes K2)

    if (tid < JT) {   // pack slice atom jbase+tid into LDS, incl. certified rc2
        const int j = jbase + tid;
        const float* p = params + 22 * j;
        const float x = coords[3*j], y = coords[3*j+1], z = coords[3*j+2];
        const float re = p[0], fe = p[1], be = p[5], al = p[4], la = p[9];
        const float rei  = __builtin_amdgcn_rcpf(re);
        const float bl2  = be * LOG2E;
        const float al2  = al * LOG2E;
        const float l2fe = __builtin_amdgcn_logf(fe);   // log2

        // bisection: g(x) = l2fe - bl2*(x-1) - log2(1+(x-la)^20) + 19.93  (f = 1e-6)
        float lo = la + 1.0f, hi = la + 6.0f;
        #pragma unroll 1
        for (int it = 0; it < 28; ++it) {
            const float mid = 0.5f * (lo + hi);
            const float g   = l2fe - bl2 * (mid - 1.0f)
                            - __builtin_amdgcn_logf(1.0f + pow20f(mid - la)) + 19.93f;
            if (g > 0.0f) lo = mid; else hi = mid;
        }
        const float rc  = re * hi;                 // conservative side
        const float rc2 = fmaxf(rc * rc, 25.01f);  // phi-set (r<=5) always included

        sphi4[tid * 3 + 0] = { x, y, z, rei };
        sphi4[tid * 3 + 1] = { -bl2 * rei, bl2 + l2fe, -la, p[7] * __builtin_amdgcn_rcpf(fe) };
        sphi4[tid * 3 + 2] = { -al2 * rei, al2, -p[8], p[6] };
        float* rd = (float*)srho4 + 8 * (tid >> 1) + (tid & 1);
        rd[0] = x; rd[2] = y; rd[4] = z; rd[6] = rc2;
    }

    // i-side constants (per-thread, straight from params; L1/L2-resident)
    const float* pi = params + 22 * i;
    const float xi = coords[3*i], yi = coords[3*i+1], zi = coords[3*i+2];
    const float rei_i  = __builtin_amdgcn_rcpf(pi[0]);
    const float bl2_i  = pi[5] * LOG2E;
    const float al2_i  = pi[4] * LOG2E;
    const float c0b_i  = -bl2_i * rei_i;
    const float c1bp_i = bl2_i + __builtin_amdgcn_logf(pi[1]);
    const float c0a_i  = -al2_i * rei_i;
    const float mla_i  = -pi[9];
    const float mka_i  = -pi[8];
    const float A_i    = pi[6];
    const float Bof_i  = pi[7] * __builtin_amdgcn_rcpf(pi[1]);

    __syncthreads();

    const v2f xi2 = { xi, xi }, yi2 = { yi, yi }, zi2 = { zi, zi };
    u64 hits = 0ull;

    #pragma unroll 4
    for (int k = 0; k < JT / 2; ++k) {
        const float4 f0 = srho4[k * 2 + 0];   // x0,x1,y0,y1
        const float4 f1 = srho4[k * 2 + 1];   // z0,z1,rc2_0,rc2_1
        const v2f x01 = { f0.x, f0.y }, y01 = { f0.z, f0.w };
        const v2f z01 = { f1.x, f1.y };
        const v2f dx = x01 - xi2, dy = y01 - yi2, dz = z01 - zi2;
        const v2f r2v = dx * dx + dy * dy + dz * dz;
        if (r2v.x <= f1.z) hits |= (1ull << (2 * k));
        if (r2v.y <= f1.w) hits |= (1ull << (2 * k + 1));
    }

    const int t = i - jbase;   // slice-local index of i (may be out of range)
    float rho = 0.0f;
    u64 phim = 0ull;

    {   // phase2a: f_r for hit pairs
        u64 m = hits;
        if (t >= 0 && t < JT) m &= ~(1ull << t);   // skip self (r=0)
        while (m) {
            const int k = __builtin_ctzll(m);
            m &= m - 1;
            const float4 q0 = sphi4[k * 3 + 0];   // x,y,z,rei
            const float4 q1 = sphi4[k * 3 + 1];   // c0b,c1bp,mla,Bof
            const float dx = q0.x - xi, dy = q0.y - yi, dz = q0.z - zi;
            const float r2 = fmaf(dx, dx, fmaf(dy, dy, dz * dz));
            const float r  = __builtin_amdgcn_sqrtf(r2);
            const float fr = __builtin_amdgcn_exp2f(fmaf(r, q1.x, q1.y))
                           * __builtin_amdgcn_rcpf(1.0f + pow20f(fmaf(r, q0.w, q1.z)));
            rho += fr;
            if (r2 <= 25.0f && k > t) phim |= (1ull << k);
        }
    }
    rho_part[(size_t)s * N_ATOMS + i] = rho;

    float e = 0.0f;
    while (phim) {   // phase2b: phi for pairs within 5 A, j > i
        const int k = __builtin_ctzll(phim);
        phim &= phim - 1;
        const float4 q0 = sphi4[k * 3 + 0];
        const float4 q1 = sphi4[k * 3 + 1];
        const float4 q2 = sphi4[k * 3 + 2];
        const float dx = q0.x - xi, dy = q0.y - yi, dz = q0.z - zi;
        const float r = __builtin_amdgcn_sqrtf(fmaf(dx, dx, fmaf(dy, dy, dz * dz)));

        const float fri = __builtin_amdgcn_exp2f(fmaf(r, c0b_i, c1bp_i))
                        * __builtin_amdgcn_rcpf(1.0f + pow20f(fmaf(r, rei_i, mla_i)));
        const float frj = __builtin_amdgcn_exp2f(fmaf(r, q1.x, q1.y))
                        * __builtin_amdgcn_rcpf(1.0f + pow20f(fmaf(r, q0.w, q1.z)));
        const float ph_i = A_i * __builtin_amdgcn_exp2f(fmaf(r, c0a_i, al2_i))
                               * __builtin_amdgcn_rcpf(1.0f + pow20f(fmaf(r, rei_i, mka_i)))
                         - Bof_i * fri;
        const float ph_j = q2.w * __builtin_amdgcn_exp2f(fmaf(r, q2.x, q2.y))
                                * __builtin_amdgcn_rcpf(1.0f + pow20f(fmaf(r, q0.w, q2.z)))
                         - q1.w * frj;
        // frj/fri*ph_i + fri/frj*ph_j = (frj^2*ph_i + fri^2*ph_j)/(fri*frj)
        e += 0.5f * fmaf(frj * frj, ph_i, fri * fri * ph_j)
                  * __builtin_amdgcn_rcpf(fri * frj);
    }

    const float eb = block_reduce(e, red);
    if (tid == 0) e_part[bi * NJ + s] = eb;
}

// K2: embed + per-tile reduction + (last block) final sum. 16 blocks x 1024 threads.
__global__ __launch_bounds__(1024) void eam_embed(
    const float* __restrict__ params,
    const float* __restrict__ rho_part, const float* __restrict__ e_part,
    float* __restrict__ tile_sum,    // [16]
    int* __restrict__ ctr, float* __restrict__ out)
{
    __shared__ float acc[4][256];
    __shared__ float red16[16];
    __shared__ int sLast;
    const int tid = threadIdx.x;
    const int b   = blockIdx.x;
    const int al  = tid & 255;       // atom within tile
    const int q   = tid >> 8;        // quarter 0..3
    const int i   = b * 256 + al;

    float part = 0.0f;
    #pragma unroll 4
    for (int s = q * 16; s < q * 16 + 16; ++s)
        part += rho_part[(size_t)s * N_ATOMS + i];   // coalesced per s
    acc[q][al] = part;
    __syncthreads();

    float v = 0.0f;
    if (tid < 256) {
        const float rhoi = (acc[0][tid] + acc[1][tid]) + (acc[2][tid] + acc[3][tid]);
        const float* p = params + 22 * i;
        float F;
        if (rhoi < p[20]) {
            const float xn = rhoi / p[20] - 1.0f;
            F = p[10] + xn * (p[11] + xn * (p[12] + xn * p[13]));
        } else if (rhoi < p[21]) {
            const float xe = rhoi / p[2] - 1.0f;
            F = p[14] + xe * (p[15] + xe * (p[16] + xe * p[17]));
        } else {
            const float l2 = __builtin_amdgcn_logf(rhoi / p[3]);   // log2
            const float tt = __builtin_amdgcn_exp2f(p[18] * l2);
            const float lt = p[18] * l2 * LN2;                     // ln
            F = p[19] * (1.0f - lt) * tt;
        }
        v = F + ((tid < NJ) ? e_part[b * NJ + tid] : 0.0f);
    }

    // deterministic reduction over 1024 threads (v = 0 for tid >= 256)
    #pragma unroll
    for (int off = 32; off > 0; off >>= 1) v += __shfl_down(v, off, 64);
    if ((tid & 63) == 0) red16[tid >> 6] = v;
    __syncthreads();
    if (tid == 0) {
        float sum = 0.0f;
        #pragma unroll
        for (int w = 0; w < 16; ++w) sum += red16[w];
        tile_sum[b] = sum;
        // release: tile_sum visible device-wide before the count (16 blocks only)
        int prev = __hip_atomic_fetch_add(ctr, 1, __ATOMIC_ACQ_REL,
                                          __HIP_MEMORY_SCOPE_AGENT);
        sLast = (prev == NTILE - 1);
    }
    __syncthreads();

    if (sLast && tid == 0) {   // last block: fixed-order final sum
        float total = 0.0f;
        #pragma unroll
        for (int w = 0; w < NTILE; ++w) total += tile_sum[w];
        out[0] = total;
    }
}

extern "C" void kernel_launch(void* const* d_in, const int* in_sizes, int n_in,
                              void* d_out, int out_size, void* d_ws, size_t ws_size,
                              hipStream_t stream) {
    const float* coords = (const float*)d_in[0];   // [4096][3]
    const float* params = (const float*)d_in[1];   // [4096][22]
    float* out = (float*)d_out;

    float* rho_part = (float*)d_ws;                          // [64][4096]
    float* e_part   = rho_part + (size_t)NJ * N_ATOMS;       // [1024]
    float* tile_sum = e_part + NTILE * NJ;                   // [16]
    int*   ctr      = (int*)(tile_sum + NTILE);              // [1]

    dim3 grid(NTILE, NJ);
    eam_main<<<grid, 256, 0, stream>>>(coords, params, rho_part, e_part, ctr);
    eam_embed<<<NTILE, 1024, 0, stream>>>(params, rho_part, e_part, tile_sum, ctr, out);
}